// Round 13
// baseline (5264.772 us; speedup 1.0000x reference)
//
#include <hip/hip_runtime.h>
#include <hip/hip_fp16.h>
#include <cstdint>

#define NN 50000
#define NQBLK 12500             // k_q blocks: NN*64/256
#define NGBLK 12500             // gather blocks: 4 nodes/block (1 per wave)
#define EPSV 1e-5f

// bucket sort params
#define NPB 128                 // nodes per bucket
#define BSH 7                   // log2(NPB)
#define NBKT 391                // ceil(NN/NPB)
#define CHUNK 4096              // edges per stage-1 block
#define EPT 16                  // edges per thread (CHUNK/256)
#define LDSE 6144               // per-bucket LDS edge capacity

// BN partial-sum spreading (R11 lesson: one hot line cost ~120us/kernel)
#define NSLOT 128

typedef unsigned short ushort_t;
typedef _Float16 half2v __attribute__((ext_vector_type(2)));

// ---------------- stage 1: per-chunk bucket histogram (+ zero BN slots/tickets) ----------------
__global__ __launch_bounds__(256) void k_hist1(const int* __restrict__ dst, int E, int nchunk,
                                               int* __restrict__ hist, float* __restrict__ gsumsp,
                                               int* __restrict__ tickets) {
    __shared__ int cnt[NBKT];
    int t = threadIdx.x, blk = blockIdx.x;
    if (blk == 0) {
        for (int z = t; z < 5 * NSLOT * 8; z += 256) gsumsp[z] = 0.f;
        if (t < 5) tickets[t] = 0;
    }
    for (int b = t; b < NBKT; b += 256) cnt[b] = 0;
    __syncthreads();
    int base = blk * CHUNK;
#pragma unroll
    for (int k = 0; k < EPT; ++k) {
        int e = base + k * 256 + t;
        if (e < E) atomicAdd(&cnt[dst[e] >> BSH], 1);
    }
    __syncthreads();
    for (int b = t; b < NBKT; b += 256) hist[(size_t)b * nchunk + blk] = cnt[b];
}

// ---------------- generic hierarchical exclusive scan ----------------
__global__ __launch_bounds__(256) void k_scanA(const int* __restrict__ in, int n,
                                               int* __restrict__ presum, int* __restrict__ blocksum) {
    __shared__ int lds[256];
    int t = threadIdx.x, g = blockIdx.x * 256 + t;
    int v = (g < n) ? in[g] : 0;
    lds[t] = v;
    __syncthreads();
    for (int off = 1; off < 256; off <<= 1) {
        int x = (t >= off) ? lds[t - off] : 0;
        __syncthreads();
        lds[t] += x;
        __syncthreads();
    }
    if (g < n) presum[g] = lds[t];
    if (t == 255) blocksum[blockIdx.x] = lds[255];
}

__global__ __launch_bounds__(256) void k_scanB(const int* __restrict__ blocksum,
                                               int nb, int* __restrict__ blockoff) {
    __shared__ int lds[256];
    __shared__ int carry_s;
    int t = threadIdx.x;
    if (t == 0) carry_s = 0;
    __syncthreads();
    for (int base = 0; base < nb; base += 256) {
        int g = base + t;
        int v = (g < nb) ? blocksum[g] : 0;
        lds[t] = v;
        __syncthreads();
        for (int off = 1; off < 256; off <<= 1) {
            int x = (t >= off) ? lds[t - off] : 0;
            __syncthreads();
            lds[t] += x;
            __syncthreads();
        }
        if (g < nb) blockoff[g] = lds[t] - v + carry_s;
        __syncthreads();
        if (t == 255) carry_s += lds[255];
        __syncthreads();
    }
}

__global__ __launch_bounds__(256) void k_scanC(const int* __restrict__ presum,
                                               const int* __restrict__ hist,
                                               const int* __restrict__ blockoff,
                                               int n, int nchunk, int* __restrict__ offsT) {
    int g = blockIdx.x * 256 + threadIdx.x;
    if (g < n) {
        int val = presum[g] - hist[g] + blockoff[blockIdx.x];
        int b = g / nchunk;
        int c = g - b * nchunk;
        offsT[(size_t)c * NBKT + b] = val;
    }
}

// ---------------- stage 1: partition edges into buckets ----------------
__global__ __launch_bounds__(256) void k_scatter1(const int* __restrict__ src,
                                                  const int* __restrict__ dst, int E,
                                                  const int* __restrict__ offsT,
                                                  int* __restrict__ ebuf) {
    __shared__ int pos[NBKT];
    int t = threadIdx.x, blk = blockIdx.x;
    for (int b = t; b < NBKT; b += 256) pos[b] = offsT[(size_t)blk * NBKT + b];
    __syncthreads();
    int base = blk * CHUNK;
#pragma unroll
    for (int k = 0; k < EPT; ++k) {
        int e = base + k * 256 + t;
        if (e < E) {
            int d = dst[e];
            int b = d >> BSH;
            int p = atomicAdd(&pos[b], 1);
            ebuf[p] = ((d & (NPB - 1)) << 16) | src[e];
        }
    }
}

// ---------------- stage 2: per-bucket CSR ----------------
__global__ __launch_bounds__(256) void k_bucket_csr(const int* __restrict__ ebuf,
                                                    const int* __restrict__ offsT, int E,
                                                    int* __restrict__ rowstart,
                                                    ushort_t* __restrict__ colsrc) {
    __shared__ int cnt[NPB];
    __shared__ int s[NPB];
    __shared__ int pos2[NPB];
    __shared__ ushort_t lout[LDSE];
    int t = threadIdx.x, b = blockIdx.x;
    int bstart = offsT[b];
    int bend = (b + 1 < NBKT) ? offsT[b + 1] : E;
    int m = bend - bstart;
    if (t < NPB) cnt[t] = 0;
    __syncthreads();
    for (int i = bstart + t; i < bend; i += 256) atomicAdd(&cnt[ebuf[i] >> 16], 1);
    __syncthreads();
    if (t < NPB) s[t] = cnt[t];
    __syncthreads();
    for (int off = 1; off < NPB; off <<= 1) {
        int x = (t < NPB && t >= off) ? s[t - off] : 0;
        __syncthreads();
        if (t < NPB) s[t] += x;
        __syncthreads();
    }
    if (t < NPB) {
        int excl = s[t] - cnt[t];
        int node = b * NPB + t;
        if (node < NN) rowstart[node] = bstart + excl;
        pos2[t] = excl;
    }
    __syncthreads();
    if (m <= LDSE) {
        for (int i = bstart + t; i < bend; i += 256) {
            int v = ebuf[i];
            int p = atomicAdd(&pos2[v >> 16], 1);
            lout[p] = (ushort_t)(v & 0xFFFF);
        }
        __syncthreads();
        for (int i = t; i < m; i += 256) colsrc[bstart + i] = lout[i];
    } else {
        for (int i = bstart + t; i < bend; i += 256) {
            int v = ebuf[i];
            int p = atomicAdd(&pos2[v >> 16], 1);
            colsrc[bstart + p] = (ushort_t)(v & 0xFFFF);
        }
    }
    if (b == NBKT - 1 && t == 0) rowstart[NN] = E;
}

// ---------------- per-layer: node -> (q_s, q_d) in fp16 ----------------
__global__ __launch_bounds__(256) void k_q(
    const float* __restrict__ pin, int pstride, int c0, int c1, int c2,
    const float* __restrict__ W1l, const float* __restrict__ b1l,
    const float* __restrict__ scale, const float* __restrict__ shift, int use_bn,
    __half* __restrict__ qs, __half* __restrict__ qd) {
    int idx = blockIdx.x * 256 + threadIdx.x;   // v*64 + c
    int v = idx >> 6, c = idx & 63;
    const float* prow = pin + (size_t)v * pstride;
    float p0 = prow[c0], p1 = prow[c1], p2 = prow[c2];
    if (use_bn) {
        p0 = fmaxf(0.f, p0 * scale[0] + shift[0]);
        p1 = fmaxf(0.f, p1 * scale[1] + shift[1]);
        p2 = fmaxf(0.f, p2 * scale[2] + shift[2]);
    }
    float w0 = W1l[0 * 64 + c], w1 = W1l[1 * 64 + c], w2 = W1l[2 * 64 + c];
    float w3 = W1l[3 * 64 + c], w4 = W1l[4 * 64 + c], w5 = W1l[5 * 64 + c];
    qs[idx] = __float2half(p0 * w0 + p1 * w1 + p2 * w2);
    qd[idx] = __float2half(p0 * (w3 - w0) + p1 * (w4 - w1) + p2 * (w5 - w2) + b1l[c]);
}

// ---------------- vectorized edge accumulation (R7 form — DO NOT MODIFY) ----------------
// All 8 dwordx4 loads issued unconditionally before any consume. Masked slots
// load row 0 (always-hot line). R9: branches here break the load clause.
// R12: do NOT wrap callers in multi-node loops — VGPR blowup kills occupancy.
__device__ __forceinline__ half2v bitcast_h2(unsigned int u) {
    union { unsigned int u; half2v h; } cvt;
    cvt.u = u;
    return cvt.h;
}

__device__ __forceinline__ void accum8f(const char* __restrict__ qsb, unsigned int byteoff,
                                        const half2v qd2[4], float acc[8]) {
    uint4 q = *reinterpret_cast<const uint4*>(qsb + byteoff);
    unsigned int wd[4] = {q.x, q.y, q.z, q.w};
    const half2v z2 = {(_Float16)0.0f, (_Float16)0.0f};
#pragma unroll
    for (int d = 0; d < 4; ++d) {
        half2v r = bitcast_h2(wd[d]) + qd2[d];
        r = __builtin_elementwise_max(r, z2);
        acc[2 * d]     += (float)r.x;
        acc[2 * d + 1] += (float)r.y;
    }
}

__device__ __forceinline__ void edge_loop(const char* __restrict__ qsb,
                                          const ushort_t* __restrict__ colsrc,
                                          int start, int end, int es, int cg,
                                          const half2v qd2[4], float acc[8]) {
    int lane = (es << 3) | cg;
    unsigned int cg16 = (unsigned int)(cg << 4);
    const half2v z2 = {(_Float16)0.0f, (_Float16)0.0f};
    int i = start;
    while (i < end) {
        int cnt = min(64, end - i);
        int sl = (lane < cnt) ? (int)colsrc[i + lane] : 0;
        uint4 q[8];
#pragma unroll
        for (int k = 0; k < 8; ++k) {
            int s = __shfl(sl, (k << 3) + es);
            q[k] = *reinterpret_cast<const uint4*>(qsb + (((unsigned int)(s << 7)) | cg16));
        }
        half2v h[4] = {z2, z2, z2, z2};
#pragma unroll
        for (int k = 0; k < 8; ++k) {
            bool ok = ((k << 3) + es) < cnt;
            unsigned int wd[4] = {q[k].x, q[k].y, q[k].z, q[k].w};
#pragma unroll
            for (int d = 0; d < 4; ++d) {
                half2v r = bitcast_h2(wd[d]) + qd2[d];      // v_pk_add_f16
                r = __builtin_elementwise_max(r, z2);       // v_pk_max_f16
                h[d] += ok ? r : z2;                        // cndmask + v_pk_add_f16
            }
        }
#pragma unroll
        for (int d = 0; d < 4; ++d) {
            acc[2 * d]     += (float)h[d].x;
            acc[2 * d + 1] += (float)h[d].y;
        }
        i += cnt;
    }
}

// ---------------- gather + reduce, layers 0..4; BN finalize fused in last block ----------------
__global__ __launch_bounds__(256) void k_gather3(
    const __half* __restrict__ qs, const __half* __restrict__ qd,
    const int* __restrict__ rowstart, const ushort_t* __restrict__ colsrc,
    const float* __restrict__ W2l, const float* __restrict__ b2l,
    const float* __restrict__ gamma_l, const float* __restrict__ beta_l,
    float* __restrict__ pnext, float* __restrict__ gsum_l,
    int* __restrict__ ticket_l, float* __restrict__ scale, float* __restrict__ shift) {
    __shared__ float w2c[3][64];
    __shared__ float b2c[3];
    __shared__ float part[4][8];
    __shared__ float red[6][8];
    __shared__ float tot[6];
    __shared__ int is_last;
    int tid = threadIdx.x;
    if (tid < 192) {
        int cj = tid >> 6;
        int col = (cj == 0) ? 0 : ((cj == 1) ? 1 : 14);
        w2c[cj][tid & 63] = W2l[(tid & 63) * 64 + col];
    }
    if (tid < 3) b2c[tid] = b2l[(tid == 0) ? 0 : ((tid == 1) ? 1 : 14)];
    __syncthreads();

    int w = tid >> 6, lane = tid & 63;
    int es = lane >> 3, cg = lane & 7;
    int v = blockIdx.x * 4 + w;
    const char* qsb = (const char*)qs;
    uint4 qq = ((const uint4*)qd)[(size_t)v * 8 + cg];
    unsigned int qw[4] = {qq.x, qq.y, qq.z, qq.w};
    half2v qd2[4];
#pragma unroll
    for (int d = 0; d < 4; ++d) qd2[d] = bitcast_h2(qw[d]);

    float acc[8] = {0, 0, 0, 0, 0, 0, 0, 0};
    int start = rowstart[v], end = rowstart[v + 1];
    if (es == 0) accum8f(qsb, ((unsigned int)(v << 7)) | (cg << 4), qd2, acc);  // self loop
    edge_loop(qsb, colsrc, start, end, es, cg, qd2, acc);

#pragma unroll
    for (int k = 0; k < 8; ++k) {
        acc[k] += __shfl_xor(acc[k], 8);
        acc[k] += __shfl_xor(acc[k], 16);
        acc[k] += __shfl_xor(acc[k], 32);
    }
    float degp1 = (float)(end - start + 1);
#pragma unroll
    for (int j = 0; j < 3; ++j) {
        float t = 0.f;
#pragma unroll
        for (int k = 0; k < 8; ++k) t += acc[k] * w2c[j][cg * 8 + k];
        t += __shfl_xor(t, 1);
        t += __shfl_xor(t, 2);
        t += __shfl_xor(t, 4);
        if (lane == 0) {
            float val = t + degp1 * b2c[j];
            pnext[v * 3 + j] = val;
            part[w][j] = val;
            part[w][3 + j] = val * val;
        }
    }
    __syncthreads();
    if (tid < 6) {
        float ssum = part[0][tid] + part[1][tid] + part[2][tid] + part[3][tid];
        // spread over 128 slots (64 lines) -> no single-line contention (R11)
        atomicAdd(&gsum_l[(blockIdx.x & (NSLOT - 1)) * 8 + tid], ssum);
    }
    // ---- last-block BN finalize (replaces the k_bnfin launch) ----
    __threadfence();
    __syncthreads();
    if (tid == 0) {
        int old = atomicAdd(ticket_l, 1);
        is_last = (old == (int)gridDim.x - 1) ? 1 : 0;
    }
    __syncthreads();
    if (is_last) {
        __threadfence();
        if (tid < 48) {
            int j = tid >> 3, k = tid & 7;
            float s = 0.f;
            for (int slot = k; slot < NSLOT; slot += 8)
                s += __hip_atomic_load(&gsum_l[slot * 8 + j], __ATOMIC_RELAXED,
                                       __HIP_MEMORY_SCOPE_AGENT);
            red[j][k] = s;
        }
        __syncthreads();
        if (tid < 6) {
            float s = 0.f;
#pragma unroll
            for (int k2 = 0; k2 < 8; ++k2) s += red[tid][k2];
            tot[tid] = s;
        }
        __syncthreads();
        if (tid < 3) {
            const int cols[3] = {0, 1, 14};
            float mu = tot[tid] / (float)NN;
            float var = tot[tid + 3] / (float)NN - mu * mu;
            float rs = rsqrtf(var + EPSV);
            float g = gamma_l[cols[tid]];
            scale[tid] = rs * g;
            shift[tid] = beta_l[cols[tid]] - mu * rs * g;
        }
    }
}

// ---------------- gather + full 64-col matmul, layer 5 ----------------
__global__ __launch_bounds__(256) void k_gather_full(
    const __half* __restrict__ qs, const __half* __restrict__ qd,
    const int* __restrict__ rowstart, const ushort_t* __restrict__ colsrc,
    const float* __restrict__ W2l, const float* __restrict__ b2l,
    float* __restrict__ out) {
    __shared__ float lds[4][64];
    int tid = threadIdx.x;
    int w = tid >> 6, lane = tid & 63;
    int es = lane >> 3, cg = lane & 7;
    int v = blockIdx.x * 4 + w;
    const char* qsb = (const char*)qs;
    uint4 qq = ((const uint4*)qd)[(size_t)v * 8 + cg];
    unsigned int qw[4] = {qq.x, qq.y, qq.z, qq.w};
    half2v qd2[4];
#pragma unroll
    for (int d = 0; d < 4; ++d) qd2[d] = bitcast_h2(qw[d]);

    float acc[8] = {0, 0, 0, 0, 0, 0, 0, 0};
    int start = rowstart[v], end = rowstart[v + 1];
    if (es == 0) accum8f(qsb, ((unsigned int)(v << 7)) | (cg << 4), qd2, acc);  // self loop
    edge_loop(qsb, colsrc, start, end, es, cg, qd2, acc);

#pragma unroll
    for (int k = 0; k < 8; ++k) {
        acc[k] += __shfl_xor(acc[k], 8);
        acc[k] += __shfl_xor(acc[k], 16);
        acc[k] += __shfl_xor(acc[k], 32);
    }
    if (es == 0) {
#pragma unroll
        for (int k = 0; k < 8; ++k) lds[w][cg * 8 + k] = acc[k];
    }
    __syncthreads();
    float degp1 = (float)(end - start + 1);
    float sum = degp1 * b2l[lane];
    for (int k = 0; k < 64; ++k) sum += lds[w][k] * W2l[k * 64 + lane];
    out[(size_t)v * 64 + lane] = sum;
}

// ---------------- launch ----------------

static inline size_t align_up(size_t x) { return (x + 255) & ~(size_t)255; }

extern "C" void kernel_launch(void* const* d_in, const int* in_sizes, int n_in,
                              void* d_out, int out_size, void* d_ws, size_t ws_size,
                              hipStream_t stream) {
    const float* x     = (const float*)d_in[0];
    const int*   ei    = (const int*)d_in[1];
    const float* W1    = (const float*)d_in[2];
    const float* b1    = (const float*)d_in[3];
    const float* W2    = (const float*)d_in[4];
    const float* b2    = (const float*)d_in[5];
    const float* gamma = (const float*)d_in[6];
    const float* beta  = (const float*)d_in[7];
    float* out = (float*)d_out;
    const int E = in_sizes[1] / 2;           // 1,600,000
    const int* src = ei;
    const int* dst = ei + E;

    const int nchunk = (E + CHUNK - 1) / CHUNK;     // 391
    const int nscan  = NBKT * nchunk;
    const int nsb    = (nscan + 255) / 256;

    // workspace carve
    char* base = (char*)d_ws;
    size_t off = 0;
    __half* qs = (__half*)(base + off);     off = align_up(off + (size_t)NN * 64 * 2);
    __half* qd = (__half*)(base + off);     off = align_up(off + (size_t)NN * 64 * 2);
    float* pA = (float*)(base + off);       off = align_up(off + (size_t)NN * 3 * 4);
    float* pB = (float*)(base + off);       off = align_up(off + (size_t)NN * 3 * 4);
    int* rowstart = (int*)(base + off);     off = align_up(off + (size_t)(NN + 1) * 4);
    ushort_t* colsrc = (ushort_t*)(base + off); off = align_up(off + (size_t)E * 2);
    int* ebuf     = (int*)(base + off);     off = align_up(off + (size_t)E * 4);
    int* hist     = (int*)(base + off);     off = align_up(off + (size_t)nscan * 4);
    int* offsT    = (int*)(base + off);     off = align_up(off + (size_t)nscan * 4);
    int* presum   = (int*)(base + off);     off = align_up(off + (size_t)nscan * 4);
    int* bsum     = (int*)(base + off);     off = align_up(off + (size_t)nsb * 4);
    int* boff     = (int*)(base + off);     off = align_up(off + (size_t)nsb * 4);
    float* gsumsp = (float*)(base + off);   off = align_up(off + (size_t)5 * NSLOT * 8 * 4);
    int* tickets  = (int*)(base + off);     off = align_up(off + 5 * 4);
    float* scale  = (float*)(base + off);   off = align_up(off + 64 * 4);
    float* shift  = (float*)(base + off);   off = align_up(off + 64 * 4);
    (void)ws_size; (void)n_in; (void)out_size;

    // CSR build: two-stage counting sort (also zeros gsumsp + tickets)
    k_hist1<<<nchunk, 256, 0, stream>>>(dst, E, nchunk, hist, gsumsp, tickets);
    k_scanA<<<nsb, 256, 0, stream>>>(hist, nscan, presum, bsum);
    k_scanB<<<1, 256, 0, stream>>>(bsum, nsb, boff);
    k_scanC<<<nsb, 256, 0, stream>>>(presum, hist, boff, nscan, nchunk, offsT);
    k_scatter1<<<nchunk, 256, 0, stream>>>(src, dst, E, offsT, ebuf);
    k_bucket_csr<<<NBKT, 256, 0, stream>>>(ebuf, offsT, E, rowstart, colsrc);

    float* pc = pA;
    float* pn = pB;
    for (int l = 0; l < 6; ++l) {
        const float* pin = (l == 0) ? x : pc;
        int pstride = (l == 0) ? 16 : 3;
        int c0 = 0, c1 = 1, c2 = (l == 0) ? 14 : 2;
        k_q<<<NQBLK, 256, 0, stream>>>(pin, pstride, c0, c1, c2,
                                       W1 + (size_t)l * 6 * 64, b1 + (size_t)l * 64,
                                       scale, shift, (l > 0) ? 1 : 0, qs, qd);
        if (l < 5) {
            k_gather3<<<NGBLK, 256, 0, stream>>>(qs, qd, rowstart, colsrc,
                                                 W2 + (size_t)l * 64 * 64, b2 + (size_t)l * 64,
                                                 gamma + (size_t)l * 64, beta + (size_t)l * 64,
                                                 pn, gsumsp + (size_t)l * NSLOT * 8,
                                                 tickets + l, scale, shift);
            float* tmp = pc; pc = pn; pn = tmp;
        } else {
            k_gather_full<<<NGBLK, 256, 0, stream>>>(qs, qd, rowstart, colsrc,
                                                     W2 + (size_t)5 * 64 * 64, b2 + (size_t)5 * 64,
                                                     out);
        }
    }
}

// Round 14
// 505.807 us; speedup vs baseline: 10.4087x; 10.4087x over previous
//
#include <hip/hip_runtime.h>
#include <hip/hip_fp16.h>
#include <cstdint>

#define NN 50000
#define NQBLK 12500             // k_q blocks: NN*64/256
#define NGBLK 12500             // gather blocks: 4 nodes/block (1 per wave)
#define EPSV 1e-5f

// bucket sort params
#define NPB 128                 // nodes per bucket
#define BSH 7                   // log2(NPB)
#define NBKT 391                // ceil(NN/NPB)
#define CHUNK 4096              // edges per stage-1 block
#define EPT 16                  // edges per thread (CHUNK/256)
#define LDSE 6144               // per-bucket LDS edge capacity

// BN partial-sum spreading (R11 lesson: one hot line cost ~120us/kernel)
#define NSLOT 128

typedef unsigned short ushort_t;
typedef _Float16 half2v __attribute__((ext_vector_type(2)));

// ---------------- stage 1: per-chunk bucket histogram (+ zero BN slots) ----------------
__global__ __launch_bounds__(256) void k_hist1(const int* __restrict__ dst, int E, int nchunk,
                                               int* __restrict__ hist, float* __restrict__ gsumsp) {
    __shared__ int cnt[NBKT];
    int t = threadIdx.x, blk = blockIdx.x;
    if (blk == 0) {
        for (int z = t; z < 5 * NSLOT * 8; z += 256) gsumsp[z] = 0.f;
    }
    for (int b = t; b < NBKT; b += 256) cnt[b] = 0;
    __syncthreads();
    int base = blk * CHUNK;
#pragma unroll
    for (int k = 0; k < EPT; ++k) {
        int e = base + k * 256 + t;
        if (e < E) atomicAdd(&cnt[dst[e] >> BSH], 1);
    }
    __syncthreads();
    for (int b = t; b < NBKT; b += 256) hist[(size_t)b * nchunk + blk] = cnt[b];
}

// ---------------- generic hierarchical exclusive scan ----------------
__global__ __launch_bounds__(256) void k_scanA(const int* __restrict__ in, int n,
                                               int* __restrict__ presum, int* __restrict__ blocksum) {
    __shared__ int lds[256];
    int t = threadIdx.x, g = blockIdx.x * 256 + t;
    int v = (g < n) ? in[g] : 0;
    lds[t] = v;
    __syncthreads();
    for (int off = 1; off < 256; off <<= 1) {
        int x = (t >= off) ? lds[t - off] : 0;
        __syncthreads();
        lds[t] += x;
        __syncthreads();
    }
    if (g < n) presum[g] = lds[t];
    if (t == 255) blocksum[blockIdx.x] = lds[255];
}

__global__ __launch_bounds__(256) void k_scanB(const int* __restrict__ blocksum,
                                               int nb, int* __restrict__ blockoff) {
    __shared__ int lds[256];
    __shared__ int carry_s;
    int t = threadIdx.x;
    if (t == 0) carry_s = 0;
    __syncthreads();
    for (int base = 0; base < nb; base += 256) {
        int g = base + t;
        int v = (g < nb) ? blocksum[g] : 0;
        lds[t] = v;
        __syncthreads();
        for (int off = 1; off < 256; off <<= 1) {
            int x = (t >= off) ? lds[t - off] : 0;
            __syncthreads();
            lds[t] += x;
            __syncthreads();
        }
        if (g < nb) blockoff[g] = lds[t] - v + carry_s;
        __syncthreads();
        if (t == 255) carry_s += lds[255];
        __syncthreads();
    }
}

__global__ __launch_bounds__(256) void k_scanC(const int* __restrict__ presum,
                                               const int* __restrict__ hist,
                                               const int* __restrict__ blockoff,
                                               int n, int nchunk, int* __restrict__ offsT) {
    int g = blockIdx.x * 256 + threadIdx.x;
    if (g < n) {
        int val = presum[g] - hist[g] + blockoff[blockIdx.x];
        int b = g / nchunk;
        int c = g - b * nchunk;
        offsT[(size_t)c * NBKT + b] = val;
    }
}

// ---------------- stage 1: partition edges into buckets ----------------
__global__ __launch_bounds__(256) void k_scatter1(const int* __restrict__ src,
                                                  const int* __restrict__ dst, int E,
                                                  const int* __restrict__ offsT,
                                                  int* __restrict__ ebuf) {
    __shared__ int pos[NBKT];
    int t = threadIdx.x, blk = blockIdx.x;
    for (int b = t; b < NBKT; b += 256) pos[b] = offsT[(size_t)blk * NBKT + b];
    __syncthreads();
    int base = blk * CHUNK;
#pragma unroll
    for (int k = 0; k < EPT; ++k) {
        int e = base + k * 256 + t;
        if (e < E) {
            int d = dst[e];
            int b = d >> BSH;
            int p = atomicAdd(&pos[b], 1);
            ebuf[p] = ((d & (NPB - 1)) << 16) | src[e];
        }
    }
}

// ---------------- stage 2: per-bucket CSR ----------------
__global__ __launch_bounds__(256) void k_bucket_csr(const int* __restrict__ ebuf,
                                                    const int* __restrict__ offsT, int E,
                                                    int* __restrict__ rowstart,
                                                    ushort_t* __restrict__ colsrc) {
    __shared__ int cnt[NPB];
    __shared__ int s[NPB];
    __shared__ int pos2[NPB];
    __shared__ ushort_t lout[LDSE];
    int t = threadIdx.x, b = blockIdx.x;
    int bstart = offsT[b];
    int bend = (b + 1 < NBKT) ? offsT[b + 1] : E;
    int m = bend - bstart;
    if (t < NPB) cnt[t] = 0;
    __syncthreads();
    for (int i = bstart + t; i < bend; i += 256) atomicAdd(&cnt[ebuf[i] >> 16], 1);
    __syncthreads();
    if (t < NPB) s[t] = cnt[t];
    __syncthreads();
    for (int off = 1; off < NPB; off <<= 1) {
        int x = (t < NPB && t >= off) ? s[t - off] : 0;
        __syncthreads();
        if (t < NPB) s[t] += x;
        __syncthreads();
    }
    if (t < NPB) {
        int excl = s[t] - cnt[t];
        int node = b * NPB + t;
        if (node < NN) rowstart[node] = bstart + excl;
        pos2[t] = excl;
    }
    __syncthreads();
    if (m <= LDSE) {
        for (int i = bstart + t; i < bend; i += 256) {
            int v = ebuf[i];
            int p = atomicAdd(&pos2[v >> 16], 1);
            lout[p] = (ushort_t)(v & 0xFFFF);
        }
        __syncthreads();
        for (int i = t; i < m; i += 256) colsrc[bstart + i] = lout[i];
    } else {
        for (int i = bstart + t; i < bend; i += 256) {
            int v = ebuf[i];
            int p = atomicAdd(&pos2[v >> 16], 1);
            colsrc[bstart + p] = (ushort_t)(v & 0xFFFF);
        }
    }
    if (b == NBKT - 1 && t == 0) rowstart[NN] = E;
}

// ---------------- per-layer: node -> (q_s, q_d); BN finalize as per-block preamble ----------------
// Each block redundantly reduces the 128x8 spread slots (4 KB, L2-hot) -> no
// cross-block communication, no fences (R13 lesson: per-block __threadfence
// wrecks the XCD L2s). Visibility of gsum_prev comes from stream ordering.
__global__ __launch_bounds__(256) void k_q(
    const float* __restrict__ pin, int pstride, int c0, int c1, int c2,
    const float* __restrict__ W1l, const float* __restrict__ b1l,
    const float* __restrict__ gsum_prev, const float* __restrict__ gamma_prev,
    const float* __restrict__ beta_prev, int use_bn,
    __half* __restrict__ qs, __half* __restrict__ qd) {
    __shared__ float red[6][8];
    __shared__ float ss[6];      // scale[0..2], shift[3..5]
    int t = threadIdx.x;
    if (use_bn) {
        if (t < 48) {
            int j = t >> 3, k = t & 7;
            float s = 0.f;
            for (int slot = k; slot < NSLOT; slot += 8) s += gsum_prev[slot * 8 + j];
            red[j][k] = s;
        }
        __syncthreads();
        if (t < 3) {
            const int cols[3] = {0, 1, 14};
            float sm = 0.f, sq = 0.f;
#pragma unroll
            for (int k2 = 0; k2 < 8; ++k2) { sm += red[t][k2]; sq += red[t + 3][k2]; }
            float mu = sm / (float)NN;
            float var = sq / (float)NN - mu * mu;
            float rs = rsqrtf(var + EPSV);
            float g = gamma_prev[cols[t]];
            ss[t] = rs * g;
            ss[t + 3] = beta_prev[cols[t]] - mu * rs * g;
        }
        __syncthreads();
    }
    int idx = blockIdx.x * 256 + t;             // v*64 + c
    int v = idx >> 6, c = idx & 63;
    const float* prow = pin + (size_t)v * pstride;
    float p0 = prow[c0], p1 = prow[c1], p2 = prow[c2];
    if (use_bn) {
        p0 = fmaxf(0.f, p0 * ss[0] + ss[3]);
        p1 = fmaxf(0.f, p1 * ss[1] + ss[4]);
        p2 = fmaxf(0.f, p2 * ss[2] + ss[5]);
    }
    float w0 = W1l[0 * 64 + c], w1 = W1l[1 * 64 + c], w2 = W1l[2 * 64 + c];
    float w3 = W1l[3 * 64 + c], w4 = W1l[4 * 64 + c], w5 = W1l[5 * 64 + c];
    qs[idx] = __float2half(p0 * w0 + p1 * w1 + p2 * w2);
    qd[idx] = __float2half(p0 * (w3 - w0) + p1 * (w4 - w1) + p2 * (w5 - w2) + b1l[c]);
}

// ---------------- vectorized edge accumulation (R7 form — DO NOT MODIFY) ----------------
// All 8 dwordx4 loads issued unconditionally before any consume. Masked slots
// load row 0 (always-hot line). R9: branches here break the load clause.
// R12: no multi-node outer loops (VGPR blowup). R13: no device fences.
__device__ __forceinline__ half2v bitcast_h2(unsigned int u) {
    union { unsigned int u; half2v h; } cvt;
    cvt.u = u;
    return cvt.h;
}

__device__ __forceinline__ void accum8f(const char* __restrict__ qsb, unsigned int byteoff,
                                        const half2v qd2[4], float acc[8]) {
    uint4 q = *reinterpret_cast<const uint4*>(qsb + byteoff);
    unsigned int wd[4] = {q.x, q.y, q.z, q.w};
    const half2v z2 = {(_Float16)0.0f, (_Float16)0.0f};
#pragma unroll
    for (int d = 0; d < 4; ++d) {
        half2v r = bitcast_h2(wd[d]) + qd2[d];
        r = __builtin_elementwise_max(r, z2);
        acc[2 * d]     += (float)r.x;
        acc[2 * d + 1] += (float)r.y;
    }
}

__device__ __forceinline__ void edge_loop(const char* __restrict__ qsb,
                                          const ushort_t* __restrict__ colsrc,
                                          int start, int end, int es, int cg,
                                          const half2v qd2[4], float acc[8]) {
    int lane = (es << 3) | cg;
    unsigned int cg16 = (unsigned int)(cg << 4);
    const half2v z2 = {(_Float16)0.0f, (_Float16)0.0f};
    int i = start;
    while (i < end) {
        int cnt = min(64, end - i);
        int sl = (lane < cnt) ? (int)colsrc[i + lane] : 0;
        uint4 q[8];
#pragma unroll
        for (int k = 0; k < 8; ++k) {
            int s = __shfl(sl, (k << 3) + es);
            q[k] = *reinterpret_cast<const uint4*>(qsb + (((unsigned int)(s << 7)) | cg16));
        }
        half2v h[4] = {z2, z2, z2, z2};
#pragma unroll
        for (int k = 0; k < 8; ++k) {
            bool ok = ((k << 3) + es) < cnt;
            unsigned int wd[4] = {q[k].x, q[k].y, q[k].z, q[k].w};
#pragma unroll
            for (int d = 0; d < 4; ++d) {
                half2v r = bitcast_h2(wd[d]) + qd2[d];      // v_pk_add_f16
                r = __builtin_elementwise_max(r, z2);       // v_pk_max_f16
                h[d] += ok ? r : z2;                        // cndmask + v_pk_add_f16
            }
        }
#pragma unroll
        for (int d = 0; d < 4; ++d) {
            acc[2 * d]     += (float)h[d].x;
            acc[2 * d + 1] += (float)h[d].y;
        }
        i += cnt;
    }
}

// ---------------- gather + reduce, layers 0..4 (3 output cols) ----------------
__global__ __launch_bounds__(256) void k_gather3(
    const __half* __restrict__ qs, const __half* __restrict__ qd,
    const int* __restrict__ rowstart, const ushort_t* __restrict__ colsrc,
    const float* __restrict__ W2l, const float* __restrict__ b2l,
    float* __restrict__ pnext, float* __restrict__ gsum_l) {
    __shared__ float w2c[3][64];
    __shared__ float b2c[3];
    __shared__ float part[4][8];
    int tid = threadIdx.x;
    if (tid < 192) {
        int cj = tid >> 6;
        int col = (cj == 0) ? 0 : ((cj == 1) ? 1 : 14);
        w2c[cj][tid & 63] = W2l[(tid & 63) * 64 + col];
    }
    if (tid < 3) b2c[tid] = b2l[(tid == 0) ? 0 : ((tid == 1) ? 1 : 14)];
    __syncthreads();

    int w = tid >> 6, lane = tid & 63;
    int es = lane >> 3, cg = lane & 7;
    int v = blockIdx.x * 4 + w;
    const char* qsb = (const char*)qs;
    uint4 qq = ((const uint4*)qd)[(size_t)v * 8 + cg];
    unsigned int qw[4] = {qq.x, qq.y, qq.z, qq.w};
    half2v qd2[4];
#pragma unroll
    for (int d = 0; d < 4; ++d) qd2[d] = bitcast_h2(qw[d]);

    float acc[8] = {0, 0, 0, 0, 0, 0, 0, 0};
    int start = rowstart[v], end = rowstart[v + 1];
    if (es == 0) accum8f(qsb, ((unsigned int)(v << 7)) | (cg << 4), qd2, acc);  // self loop
    edge_loop(qsb, colsrc, start, end, es, cg, qd2, acc);

#pragma unroll
    for (int k = 0; k < 8; ++k) {
        acc[k] += __shfl_xor(acc[k], 8);
        acc[k] += __shfl_xor(acc[k], 16);
        acc[k] += __shfl_xor(acc[k], 32);
    }
    float degp1 = (float)(end - start + 1);
#pragma unroll
    for (int j = 0; j < 3; ++j) {
        float t = 0.f;
#pragma unroll
        for (int k = 0; k < 8; ++k) t += acc[k] * w2c[j][cg * 8 + k];
        t += __shfl_xor(t, 1);
        t += __shfl_xor(t, 2);
        t += __shfl_xor(t, 4);
        if (lane == 0) {
            float val = t + degp1 * b2c[j];
            pnext[v * 3 + j] = val;
            part[w][j] = val;
            part[w][3 + j] = val * val;
        }
    }
    __syncthreads();
    if (tid < 6) {
        float ssum = part[0][tid] + part[1][tid] + part[2][tid] + part[3][tid];
        // spread over 128 slots (64 lines) -> no single-line contention (R11)
        atomicAdd(&gsum_l[(blockIdx.x & (NSLOT - 1)) * 8 + tid], ssum);
    }
}

// ---------------- gather + full 64-col matmul, layer 5 ----------------
__global__ __launch_bounds__(256) void k_gather_full(
    const __half* __restrict__ qs, const __half* __restrict__ qd,
    const int* __restrict__ rowstart, const ushort_t* __restrict__ colsrc,
    const float* __restrict__ W2l, const float* __restrict__ b2l,
    float* __restrict__ out) {
    __shared__ float lds[4][64];
    int tid = threadIdx.x;
    int w = tid >> 6, lane = tid & 63;
    int es = lane >> 3, cg = lane & 7;
    int v = blockIdx.x * 4 + w;
    const char* qsb = (const char*)qs;
    uint4 qq = ((const uint4*)qd)[(size_t)v * 8 + cg];
    unsigned int qw[4] = {qq.x, qq.y, qq.z, qq.w};
    half2v qd2[4];
#pragma unroll
    for (int d = 0; d < 4; ++d) qd2[d] = bitcast_h2(qw[d]);

    float acc[8] = {0, 0, 0, 0, 0, 0, 0, 0};
    int start = rowstart[v], end = rowstart[v + 1];
    if (es == 0) accum8f(qsb, ((unsigned int)(v << 7)) | (cg << 4), qd2, acc);  // self loop
    edge_loop(qsb, colsrc, start, end, es, cg, qd2, acc);

#pragma unroll
    for (int k = 0; k < 8; ++k) {
        acc[k] += __shfl_xor(acc[k], 8);
        acc[k] += __shfl_xor(acc[k], 16);
        acc[k] += __shfl_xor(acc[k], 32);
    }
    if (es == 0) {
#pragma unroll
        for (int k = 0; k < 8; ++k) lds[w][cg * 8 + k] = acc[k];
    }
    __syncthreads();
    float degp1 = (float)(end - start + 1);
    float sum = degp1 * b2l[lane];
    for (int k = 0; k < 64; ++k) sum += lds[w][k] * W2l[k * 64 + lane];
    out[(size_t)v * 64 + lane] = sum;
}

// ---------------- launch ----------------

static inline size_t align_up(size_t x) { return (x + 255) & ~(size_t)255; }

extern "C" void kernel_launch(void* const* d_in, const int* in_sizes, int n_in,
                              void* d_out, int out_size, void* d_ws, size_t ws_size,
                              hipStream_t stream) {
    const float* x     = (const float*)d_in[0];
    const int*   ei    = (const int*)d_in[1];
    const float* W1    = (const float*)d_in[2];
    const float* b1    = (const float*)d_in[3];
    const float* W2    = (const float*)d_in[4];
    const float* b2    = (const float*)d_in[5];
    const float* gamma = (const float*)d_in[6];
    const float* beta  = (const float*)d_in[7];
    float* out = (float*)d_out;
    const int E = in_sizes[1] / 2;           // 1,600,000
    const int* src = ei;
    const int* dst = ei + E;

    const int nchunk = (E + CHUNK - 1) / CHUNK;     // 391
    const int nscan  = NBKT * nchunk;
    const int nsb    = (nscan + 255) / 256;

    // workspace carve
    char* base = (char*)d_ws;
    size_t off = 0;
    __half* qs = (__half*)(base + off);     off = align_up(off + (size_t)NN * 64 * 2);
    __half* qd = (__half*)(base + off);     off = align_up(off + (size_t)NN * 64 * 2);
    float* pA = (float*)(base + off);       off = align_up(off + (size_t)NN * 3 * 4);
    float* pB = (float*)(base + off);       off = align_up(off + (size_t)NN * 3 * 4);
    int* rowstart = (int*)(base + off);     off = align_up(off + (size_t)(NN + 1) * 4);
    ushort_t* colsrc = (ushort_t*)(base + off); off = align_up(off + (size_t)E * 2);
    int* ebuf     = (int*)(base + off);     off = align_up(off + (size_t)E * 4);
    int* hist     = (int*)(base + off);     off = align_up(off + (size_t)nscan * 4);
    int* offsT    = (int*)(base + off);     off = align_up(off + (size_t)nscan * 4);
    int* presum   = (int*)(base + off);     off = align_up(off + (size_t)nscan * 4);
    int* bsum     = (int*)(base + off);     off = align_up(off + (size_t)nsb * 4);
    int* boff     = (int*)(base + off);     off = align_up(off + (size_t)nsb * 4);
    float* gsumsp = (float*)(base + off);   off = align_up(off + (size_t)5 * NSLOT * 8 * 4);
    (void)ws_size; (void)n_in; (void)out_size;

    // CSR build: two-stage counting sort (also zeros gsumsp)
    k_hist1<<<nchunk, 256, 0, stream>>>(dst, E, nchunk, hist, gsumsp);
    k_scanA<<<nsb, 256, 0, stream>>>(hist, nscan, presum, bsum);
    k_scanB<<<1, 256, 0, stream>>>(bsum, nsb, boff);
    k_scanC<<<nsb, 256, 0, stream>>>(presum, hist, boff, nscan, nchunk, offsT);
    k_scatter1<<<nchunk, 256, 0, stream>>>(src, dst, E, offsT, ebuf);
    k_bucket_csr<<<NBKT, 256, 0, stream>>>(ebuf, offsT, E, rowstart, colsrc);

    float* pc = pA;
    float* pn = pB;
    for (int l = 0; l < 6; ++l) {
        const float* pin = (l == 0) ? x : pc;
        int pstride = (l == 0) ? 16 : 3;
        int c0 = 0, c1 = 1, c2 = (l == 0) ? 14 : 2;
        const float* gs_prev = (l > 0) ? (gsumsp + (size_t)(l - 1) * NSLOT * 8) : gsumsp;
        const float* ga_prev = (l > 0) ? (gamma + (size_t)(l - 1) * 64) : gamma;
        const float* be_prev = (l > 0) ? (beta + (size_t)(l - 1) * 64) : beta;
        k_q<<<NQBLK, 256, 0, stream>>>(pin, pstride, c0, c1, c2,
                                       W1 + (size_t)l * 6 * 64, b1 + (size_t)l * 64,
                                       gs_prev, ga_prev, be_prev, (l > 0) ? 1 : 0, qs, qd);
        if (l < 5) {
            k_gather3<<<NGBLK, 256, 0, stream>>>(qs, qd, rowstart, colsrc,
                                                 W2 + (size_t)l * 64 * 64, b2 + (size_t)l * 64,
                                                 pn, gsumsp + (size_t)l * NSLOT * 8);
            float* tmp = pc; pc = pn; pn = tmp;
        } else {
            k_gather_full<<<NGBLK, 256, 0, stream>>>(qs, qd, rowstart, colsrc,
                                                     W2 + (size_t)5 * 64 * 64, b2 + (size_t)5 * 64,
                                                     out);
        }
    }
}

// Round 15
// 458.983 us; speedup vs baseline: 11.4705x; 1.1020x over previous
//
#include <hip/hip_runtime.h>
#include <hip/hip_fp16.h>
#include <cstdint>

#define NN 50000
#define NQBLK 12500             // k_q blocks: NN*64/256
#define NGBLK 12500             // gather blocks: 4 nodes/block (1 per wave)
#define EPSV 1e-5f

// bucket sort params
#define NPB 128                 // nodes per bucket
#define BSH 7                   // log2(NPB)
#define NBKT 391                // ceil(NN/NPB)
#define CHUNK 4096              // edges per stage-1 block
#define EPT 16                  // edges per thread (CHUNK/256)
#define LDSE 6144               // per-bucket LDS edge capacity

// BN partial-sum spreading: 128 slots x 8 floats per layer (64 cache lines).
// R9/R10 lesson: 75k atomics to ONE line cost ~120us/kernel; spread over 64
// lines the per-line rate is ~26/us -> negligible.
#define NSLOT 128

typedef unsigned short ushort_t;
typedef _Float16 half2v __attribute__((ext_vector_type(2)));

// ---------------- stage 1: per-chunk bucket histogram (+ zero BN slots) ----------------
__global__ __launch_bounds__(256) void k_hist1(const int* __restrict__ dst, int E, int nchunk,
                                               int* __restrict__ hist, float* __restrict__ gsumsp) {
    __shared__ int cnt[NBKT];
    int t = threadIdx.x, blk = blockIdx.x;
    if (blk == 0) {
        for (int z = t; z < 5 * NSLOT * 8; z += 256) gsumsp[z] = 0.f;
    }
    for (int b = t; b < NBKT; b += 256) cnt[b] = 0;
    __syncthreads();
    int base = blk * CHUNK;
#pragma unroll
    for (int k = 0; k < EPT; ++k) {
        int e = base + k * 256 + t;
        if (e < E) atomicAdd(&cnt[dst[e] >> BSH], 1);
    }
    __syncthreads();
    for (int b = t; b < NBKT; b += 256) hist[(size_t)b * nchunk + blk] = cnt[b];
}

// ---------------- generic hierarchical exclusive scan ----------------
__global__ __launch_bounds__(256) void k_scanA(const int* __restrict__ in, int n,
                                               int* __restrict__ presum, int* __restrict__ blocksum) {
    __shared__ int lds[256];
    int t = threadIdx.x, g = blockIdx.x * 256 + t;
    int v = (g < n) ? in[g] : 0;
    lds[t] = v;
    __syncthreads();
    for (int off = 1; off < 256; off <<= 1) {
        int x = (t >= off) ? lds[t - off] : 0;
        __syncthreads();
        lds[t] += x;
        __syncthreads();
    }
    if (g < n) presum[g] = lds[t];
    if (t == 255) blocksum[blockIdx.x] = lds[255];
}

__global__ __launch_bounds__(256) void k_scanB(const int* __restrict__ blocksum,
                                               int nb, int* __restrict__ blockoff) {
    __shared__ int lds[256];
    __shared__ int carry_s;
    int t = threadIdx.x;
    if (t == 0) carry_s = 0;
    __syncthreads();
    for (int base = 0; base < nb; base += 256) {
        int g = base + t;
        int v = (g < nb) ? blocksum[g] : 0;
        lds[t] = v;
        __syncthreads();
        for (int off = 1; off < 256; off <<= 1) {
            int x = (t >= off) ? lds[t - off] : 0;
            __syncthreads();
            lds[t] += x;
            __syncthreads();
        }
        if (g < nb) blockoff[g] = lds[t] - v + carry_s;
        __syncthreads();
        if (t == 255) carry_s += lds[255];
        __syncthreads();
    }
}

__global__ __launch_bounds__(256) void k_scanC(const int* __restrict__ presum,
                                               const int* __restrict__ hist,
                                               const int* __restrict__ blockoff,
                                               int n, int nchunk, int* __restrict__ offsT) {
    int g = blockIdx.x * 256 + threadIdx.x;
    if (g < n) {
        int val = presum[g] - hist[g] + blockoff[blockIdx.x];
        int b = g / nchunk;
        int c = g - b * nchunk;
        offsT[(size_t)c * NBKT + b] = val;
    }
}

// ---------------- stage 1: partition edges into buckets ----------------
__global__ __launch_bounds__(256) void k_scatter1(const int* __restrict__ src,
                                                  const int* __restrict__ dst, int E,
                                                  const int* __restrict__ offsT,
                                                  int* __restrict__ ebuf) {
    __shared__ int pos[NBKT];
    int t = threadIdx.x, blk = blockIdx.x;
    for (int b = t; b < NBKT; b += 256) pos[b] = offsT[(size_t)blk * NBKT + b];
    __syncthreads();
    int base = blk * CHUNK;
#pragma unroll
    for (int k = 0; k < EPT; ++k) {
        int e = base + k * 256 + t;
        if (e < E) {
            int d = dst[e];
            int b = d >> BSH;
            int p = atomicAdd(&pos[b], 1);
            ebuf[p] = ((d & (NPB - 1)) << 16) | src[e];
        }
    }
}

// ---------------- stage 2: per-bucket CSR ----------------
__global__ __launch_bounds__(256) void k_bucket_csr(const int* __restrict__ ebuf,
                                                    const int* __restrict__ offsT, int E,
                                                    int* __restrict__ rowstart,
                                                    ushort_t* __restrict__ colsrc) {
    __shared__ int cnt[NPB];
    __shared__ int s[NPB];
    __shared__ int pos2[NPB];
    __shared__ ushort_t lout[LDSE];
    int t = threadIdx.x, b = blockIdx.x;
    int bstart = offsT[b];
    int bend = (b + 1 < NBKT) ? offsT[b + 1] : E;
    int m = bend - bstart;
    if (t < NPB) cnt[t] = 0;
    __syncthreads();
    for (int i = bstart + t; i < bend; i += 256) atomicAdd(&cnt[ebuf[i] >> 16], 1);
    __syncthreads();
    if (t < NPB) s[t] = cnt[t];
    __syncthreads();
    for (int off = 1; off < NPB; off <<= 1) {
        int x = (t < NPB && t >= off) ? s[t - off] : 0;
        __syncthreads();
        if (t < NPB) s[t] += x;
        __syncthreads();
    }
    if (t < NPB) {
        int excl = s[t] - cnt[t];
        int node = b * NPB + t;
        if (node < NN) rowstart[node] = bstart + excl;
        pos2[t] = excl;
    }
    __syncthreads();
    if (m <= LDSE) {
        for (int i = bstart + t; i < bend; i += 256) {
            int v = ebuf[i];
            int p = atomicAdd(&pos2[v >> 16], 1);
            lout[p] = (ushort_t)(v & 0xFFFF);
        }
        __syncthreads();
        for (int i = t; i < m; i += 256) colsrc[bstart + i] = lout[i];
    } else {
        for (int i = bstart + t; i < bend; i += 256) {
            int v = ebuf[i];
            int p = atomicAdd(&pos2[v >> 16], 1);
            colsrc[bstart + p] = (ushort_t)(v & 0xFFFF);
        }
    }
    if (b == NBKT - 1 && t == 0) rowstart[NN] = E;
}

// ---------------- per-layer: node -> (q_s, q_d) in fp16 ----------------
__global__ __launch_bounds__(256) void k_q(
    const float* __restrict__ pin, int pstride, int c0, int c1, int c2,
    const float* __restrict__ W1l, const float* __restrict__ b1l,
    const float* __restrict__ scale, const float* __restrict__ shift, int use_bn,
    __half* __restrict__ qs, __half* __restrict__ qd) {
    int idx = blockIdx.x * 256 + threadIdx.x;   // v*64 + c
    int v = idx >> 6, c = idx & 63;
    const float* prow = pin + (size_t)v * pstride;
    float p0 = prow[c0], p1 = prow[c1], p2 = prow[c2];
    if (use_bn) {
        p0 = fmaxf(0.f, p0 * scale[0] + shift[0]);
        p1 = fmaxf(0.f, p1 * scale[1] + shift[1]);
        p2 = fmaxf(0.f, p2 * scale[2] + shift[2]);
    }
    float w0 = W1l[0 * 64 + c], w1 = W1l[1 * 64 + c], w2 = W1l[2 * 64 + c];
    float w3 = W1l[3 * 64 + c], w4 = W1l[4 * 64 + c], w5 = W1l[5 * 64 + c];
    qs[idx] = __float2half(p0 * w0 + p1 * w1 + p2 * w2);
    qd[idx] = __float2half(p0 * (w3 - w0) + p1 * (w4 - w1) + p2 * (w5 - w2) + b1l[c]);
}

// ---------------- vectorized edge accumulation (R7 form — DO NOT MODIFY) ----------------
// All 8 dwordx4 loads issued unconditionally before any consume. Masked slots
// load row 0 (always-hot line). R9: branches here break the load clause.
// R12: no multi-node outer loops (VGPR blowup). R13: no device fences.
__device__ __forceinline__ half2v bitcast_h2(unsigned int u) {
    union { unsigned int u; half2v h; } cvt;
    cvt.u = u;
    return cvt.h;
}

__device__ __forceinline__ void accum8f(const char* __restrict__ qsb, unsigned int byteoff,
                                        const half2v qd2[4], float acc[8]) {
    uint4 q = *reinterpret_cast<const uint4*>(qsb + byteoff);
    unsigned int wd[4] = {q.x, q.y, q.z, q.w};
    const half2v z2 = {(_Float16)0.0f, (_Float16)0.0f};
#pragma unroll
    for (int d = 0; d < 4; ++d) {
        half2v r = bitcast_h2(wd[d]) + qd2[d];
        r = __builtin_elementwise_max(r, z2);
        acc[2 * d]     += (float)r.x;
        acc[2 * d + 1] += (float)r.y;
    }
}

__device__ __forceinline__ void edge_loop(const char* __restrict__ qsb,
                                          const ushort_t* __restrict__ colsrc,
                                          int start, int end, int es, int cg,
                                          const half2v qd2[4], float acc[8]) {
    int lane = (es << 3) | cg;
    unsigned int cg16 = (unsigned int)(cg << 4);
    const half2v z2 = {(_Float16)0.0f, (_Float16)0.0f};
    int i = start;
    while (i < end) {
        int cnt = min(64, end - i);
        int sl = (lane < cnt) ? (int)colsrc[i + lane] : 0;
        uint4 q[8];
#pragma unroll
        for (int k = 0; k < 8; ++k) {
            int s = __shfl(sl, (k << 3) + es);
            q[k] = *reinterpret_cast<const uint4*>(qsb + (((unsigned int)(s << 7)) | cg16));
        }
        half2v h[4] = {z2, z2, z2, z2};
#pragma unroll
        for (int k = 0; k < 8; ++k) {
            bool ok = ((k << 3) + es) < cnt;
            unsigned int wd[4] = {q[k].x, q[k].y, q[k].z, q[k].w};
#pragma unroll
            for (int d = 0; d < 4; ++d) {
                half2v r = bitcast_h2(wd[d]) + qd2[d];      // v_pk_add_f16
                r = __builtin_elementwise_max(r, z2);       // v_pk_max_f16
                h[d] += ok ? r : z2;                        // cndmask + v_pk_add_f16
            }
        }
#pragma unroll
        for (int d = 0; d < 4; ++d) {
            acc[2 * d]     += (float)h[d].x;
            acc[2 * d + 1] += (float)h[d].y;
        }
        i += cnt;
    }
}

// ---------------- gather + reduce, layers 0..4 (3 output cols) ----------------
__global__ __launch_bounds__(256) void k_gather3(
    const __half* __restrict__ qs, const __half* __restrict__ qd,
    const int* __restrict__ rowstart, const ushort_t* __restrict__ colsrc,
    const float* __restrict__ W2l, const float* __restrict__ b2l,
    float* __restrict__ pnext, float* __restrict__ gsum_l) {
    __shared__ float w2c[3][64];
    __shared__ float b2c[3];
    __shared__ float part[4][8];
    int tid = threadIdx.x;
    if (tid < 192) {
        int cj = tid >> 6;
        int col = (cj == 0) ? 0 : ((cj == 1) ? 1 : 14);
        w2c[cj][tid & 63] = W2l[(tid & 63) * 64 + col];
    }
    if (tid < 3) b2c[tid] = b2l[(tid == 0) ? 0 : ((tid == 1) ? 1 : 14)];
    __syncthreads();

    int w = tid >> 6, lane = tid & 63;
    int es = lane >> 3, cg = lane & 7;
    int v = blockIdx.x * 4 + w;
    const char* qsb = (const char*)qs;
    uint4 qq = ((const uint4*)qd)[(size_t)v * 8 + cg];
    unsigned int qw[4] = {qq.x, qq.y, qq.z, qq.w};
    half2v qd2[4];
#pragma unroll
    for (int d = 0; d < 4; ++d) qd2[d] = bitcast_h2(qw[d]);

    float acc[8] = {0, 0, 0, 0, 0, 0, 0, 0};
    int start = rowstart[v], end = rowstart[v + 1];
    if (es == 0) accum8f(qsb, ((unsigned int)(v << 7)) | (cg << 4), qd2, acc);  // self loop
    edge_loop(qsb, colsrc, start, end, es, cg, qd2, acc);

    // fold the 8 edge-slots
#pragma unroll
    for (int k = 0; k < 8; ++k) {
        acc[k] += __shfl_xor(acc[k], 8);
        acc[k] += __shfl_xor(acc[k], 16);
        acc[k] += __shfl_xor(acc[k], 32);
    }
    float degp1 = (float)(end - start + 1);
#pragma unroll
    for (int j = 0; j < 3; ++j) {
        float t = 0.f;
#pragma unroll
        for (int k = 0; k < 8; ++k) t += acc[k] * w2c[j][cg * 8 + k];
        t += __shfl_xor(t, 1);
        t += __shfl_xor(t, 2);
        t += __shfl_xor(t, 4);
        if (lane == 0) {
            float val = t + degp1 * b2c[j];
            pnext[v * 3 + j] = val;
            part[w][j] = val;
            part[w][3 + j] = val * val;
        }
    }
    __syncthreads();
    if (tid < 6) {
        float ssum = part[0][tid] + part[1][tid] + part[2][tid] + part[3][tid];
        // spread over 128 slots (64 lines) -> no single-line contention (R11)
        atomicAdd(&gsum_l[(blockIdx.x & (NSLOT - 1)) * 8 + tid], ssum);
    }
}

// ---------------- BN finalize: 128x8 spread slots -> scale/shift ----------------
__global__ void k_bnfin(const float* __restrict__ gs,
                        const float* __restrict__ gamma_l, const float* __restrict__ beta_l,
                        float* __restrict__ scale, float* __restrict__ shift) {
    __shared__ float red[6][8];
    __shared__ float tot[6];
    int t = threadIdx.x;            // 64 threads
    int j = t >> 3, k = t & 7;
    if (j < 6) {
        float s = 0.f;
        for (int slot = k; slot < NSLOT; slot += 8) s += gs[slot * 8 + j];
        red[j][k] = s;
    }
    __syncthreads();
    if (t < 6) {
        float s = 0.f;
#pragma unroll
        for (int k2 = 0; k2 < 8; ++k2) s += red[t][k2];
        tot[t] = s;
    }
    __syncthreads();
    if (t < 3) {
        const int cols[3] = {0, 1, 14};
        float mu = tot[t] / (float)NN;
        float var = tot[t + 3] / (float)NN - mu * mu;
        float rs = rsqrtf(var + EPSV);
        float g = gamma_l[cols[t]];
        scale[t] = rs * g;
        shift[t] = beta_l[cols[t]] - mu * rs * g;
    }
}

// ---------------- gather + full 64-col matmul, layer 5 ----------------
__global__ __launch_bounds__(256) void k_gather_full(
    const __half* __restrict__ qs, const __half* __restrict__ qd,
    const int* __restrict__ rowstart, const ushort_t* __restrict__ colsrc,
    const float* __restrict__ W2l, const float* __restrict__ b2l,
    float* __restrict__ out) {
    __shared__ float lds[4][64];
    int tid = threadIdx.x;
    int w = tid >> 6, lane = tid & 63;
    int es = lane >> 3, cg = lane & 7;
    int v = blockIdx.x * 4 + w;
    const char* qsb = (const char*)qs;
    uint4 qq = ((const uint4*)qd)[(size_t)v * 8 + cg];
    unsigned int qw[4] = {qq.x, qq.y, qq.z, qq.w};
    half2v qd2[4];
#pragma unroll
    for (int d = 0; d < 4; ++d) qd2[d] = bitcast_h2(qw[d]);

    float acc[8] = {0, 0, 0, 0, 0, 0, 0, 0};
    int start = rowstart[v], end = rowstart[v + 1];
    if (es == 0) accum8f(qsb, ((unsigned int)(v << 7)) | (cg << 4), qd2, acc);  // self loop
    edge_loop(qsb, colsrc, start, end, es, cg, qd2, acc);

#pragma unroll
    for (int k = 0; k < 8; ++k) {
        acc[k] += __shfl_xor(acc[k], 8);
        acc[k] += __shfl_xor(acc[k], 16);
        acc[k] += __shfl_xor(acc[k], 32);
    }
    if (es == 0) {
#pragma unroll
        for (int k = 0; k < 8; ++k) lds[w][cg * 8 + k] = acc[k];
    }
    __syncthreads();
    float degp1 = (float)(end - start + 1);
    float sum = degp1 * b2l[lane];
    for (int k = 0; k < 64; ++k) sum += lds[w][k] * W2l[k * 64 + lane];
    out[(size_t)v * 64 + lane] = sum;
}

// ---------------- launch ----------------

static inline size_t align_up(size_t x) { return (x + 255) & ~(size_t)255; }

extern "C" void kernel_launch(void* const* d_in, const int* in_sizes, int n_in,
                              void* d_out, int out_size, void* d_ws, size_t ws_size,
                              hipStream_t stream) {
    const float* x     = (const float*)d_in[0];
    const int*   ei    = (const int*)d_in[1];
    const float* W1    = (const float*)d_in[2];
    const float* b1    = (const float*)d_in[3];
    const float* W2    = (const float*)d_in[4];
    const float* b2    = (const float*)d_in[5];
    const float* gamma = (const float*)d_in[6];
    const float* beta  = (const float*)d_in[7];
    float* out = (float*)d_out;
    const int E = in_sizes[1] / 2;           // 1,600,000
    const int* src = ei;
    const int* dst = ei + E;

    const int nchunk = (E + CHUNK - 1) / CHUNK;     // 391
    const int nscan  = NBKT * nchunk;
    const int nsb    = (nscan + 255) / 256;

    // workspace carve
    char* base = (char*)d_ws;
    size_t off = 0;
    __half* qs = (__half*)(base + off);     off = align_up(off + (size_t)NN * 64 * 2);
    __half* qd = (__half*)(base + off);     off = align_up(off + (size_t)NN * 64 * 2);
    float* pA = (float*)(base + off);       off = align_up(off + (size_t)NN * 3 * 4);
    float* pB = (float*)(base + off);       off = align_up(off + (size_t)NN * 3 * 4);
    int* rowstart = (int*)(base + off);     off = align_up(off + (size_t)(NN + 1) * 4);
    ushort_t* colsrc = (ushort_t*)(base + off); off = align_up(off + (size_t)E * 2);
    int* ebuf     = (int*)(base + off);     off = align_up(off + (size_t)E * 4);
    int* hist     = (int*)(base + off);     off = align_up(off + (size_t)nscan * 4);
    int* offsT    = (int*)(base + off);     off = align_up(off + (size_t)nscan * 4);
    int* presum   = (int*)(base + off);     off = align_up(off + (size_t)nscan * 4);
    int* bsum     = (int*)(base + off);     off = align_up(off + (size_t)nsb * 4);
    int* boff     = (int*)(base + off);     off = align_up(off + (size_t)nsb * 4);
    float* gsumsp = (float*)(base + off);   off = align_up(off + (size_t)5 * NSLOT * 8 * 4);
    float* scale  = (float*)(base + off);   off = align_up(off + 64 * 4);
    float* shift  = (float*)(base + off);   off = align_up(off + 64 * 4);
    (void)ws_size; (void)n_in; (void)out_size;

    // CSR build: two-stage counting sort, no hot-line atomics (also zeros gsumsp)
    k_hist1<<<nchunk, 256, 0, stream>>>(dst, E, nchunk, hist, gsumsp);
    k_scanA<<<nsb, 256, 0, stream>>>(hist, nscan, presum, bsum);
    k_scanB<<<1, 256, 0, stream>>>(bsum, nsb, boff);
    k_scanC<<<nsb, 256, 0, stream>>>(presum, hist, boff, nscan, nchunk, offsT);
    k_scatter1<<<nchunk, 256, 0, stream>>>(src, dst, E, offsT, ebuf);
    k_bucket_csr<<<NBKT, 256, 0, stream>>>(ebuf, offsT, E, rowstart, colsrc);

    float* pc = pA;
    float* pn = pB;
    for (int l = 0; l < 6; ++l) {
        const float* pin = (l == 0) ? x : pc;
        int pstride = (l == 0) ? 16 : 3;
        int c0 = 0, c1 = 1, c2 = (l == 0) ? 14 : 2;
        k_q<<<NQBLK, 256, 0, stream>>>(pin, pstride, c0, c1, c2,
                                       W1 + (size_t)l * 6 * 64, b1 + (size_t)l * 64,
                                       scale, shift, (l > 0) ? 1 : 0, qs, qd);
        if (l < 5) {
            k_gather3<<<NGBLK, 256, 0, stream>>>(qs, qd, rowstart, colsrc,
                                                 W2 + (size_t)l * 64 * 64, b2 + (size_t)l * 64,
                                                 pn, gsumsp + (size_t)l * NSLOT * 8);
            k_bnfin<<<1, 64, 0, stream>>>(gsumsp + (size_t)l * NSLOT * 8,
                                          gamma + (size_t)l * 64, beta + (size_t)l * 64,
                                          scale, shift);
            float* tmp = pc; pc = pn; pn = tmp;
        } else {
            k_gather_full<<<NGBLK, 256, 0, stream>>>(qs, qd, rowstart, colsrc,
                                                     W2 + (size_t)5 * 64 * 64, b2 + (size_t)5 * 64,
                                                     out);
        }
    }
}